// Round 8
// baseline (42.595 us; speedup 1.0000x reference)
//
#include <hip/hip_runtime.h>

#define B_ 2
#define C_ 256
#define HW_ 64
#define N_ 4096
#define K_SEL 1228   // int(4096*0.3)
#define MIP_ 16
#define MAGICU 0x5ca1f1a6u

__device__ __forceinline__ float sigm(float z) { return 1.0f / (1.0f + expf(-z)); }

// Single kernel: 512 blocks x 256 threads. Cross-block communication of the
// pooled means (xhT) via device-scope atomics + per-block flags.
__global__ __launch_bounds__(256, 2) void k_all(
    const float* __restrict__ x,
    const float* __restrict__ w1, const float* __restrict__ b1,
    const float* __restrict__ gam, const float* __restrict__ bet,
    const float* __restrict__ mea, const float* __restrict__ var,
    const float* __restrict__ wh, const float* __restrict__ bh,
    const float* __restrict__ ww, const float* __restrict__ bw,
    const float* __restrict__ wd1, const float* __restrict__ bd1,
    const float* __restrict__ wd2, const float* __restrict__ bd2,
    const float* __restrict__ msk,
    float* __restrict__ xhT, float* __restrict__ flags,
    float* __restrict__ out) {
  __shared__ float cwp[4][HW_];
  __shared__ float dpart[2][128][4];
  __shared__ float ahs[HW_], sds[HW_], sws[HW_], sps[HW_];
  __shared__ int icomb[4];
  __shared__ float fmn[4], fmx[4];
  __shared__ float red[15][4];
  __shared__ float ps[15];

  int bc = blockIdx.x, t = threadIdx.x;
  int b = bc >> 8, c = bc & 255;
  int wv = t >> 6, l = t & 63;

  // ========== Stage A: image -> registers, row/col means -> xhT (atomics)
  const float* xr = x + (size_t)bc * N_;
  float4 xv[4];
  #pragma unroll
  for (int it = 0; it < 4; ++it)
    xv[it] = *(const float4*)&xr[it * 1024 + t * 4];

  // row sums: group = 16 consecutive lanes covers one h per it
  float cse[4] = {0, 0, 0, 0};
  #pragma unroll
  for (int it = 0; it < 4; ++it) {
    float s = xv[it].x + xv[it].y + xv[it].z + xv[it].w;
    s += __shfl_xor(s, 1, 64);
    s += __shfl_xor(s, 2, 64);
    s += __shfl_xor(s, 4, 64);
    s += __shfl_xor(s, 8, 64);
    if ((t & 15) == 0) {
      int h = it * 16 + (t >> 4);
      atomicExch(&xhT[(((b * 2 + 0) * 64 + h) << 8) + c], s * (1.0f / 64.0f));
    }
    cse[0] += xv[it].x; cse[1] += xv[it].y;
    cse[2] += xv[it].z; cse[3] += xv[it].w;
  }
  // col sums: lanes l, l^16, l^32, l^48 share the same w-quad
  #pragma unroll
  for (int e = 0; e < 4; ++e) {
    cse[e] += __shfl_xor(cse[e], 16, 64);
    cse[e] += __shfl_xor(cse[e], 32, 64);
  }
  if (l < 16) {
    #pragma unroll
    for (int e = 0; e < 4; ++e) cwp[wv][4 * l + e] = cse[e];
  }
  __syncthreads();
  if (t < 64) {
    float cw = cwp[0][t] + cwp[1][t] + cwp[2][t] + cwp[3][t];
    atomicExch(&xhT[(((b * 2 + 1) * 64 + t) << 8) + c], cw * (1.0f / 64.0f));
  }
  __syncthreads();   // drains vmcnt: all value-exchs performed before flag
  if (t == 0) atomicExch(&flags[bc], __uint_as_float(MAGICU));

  // ========== poll: wait for all 256 producer blocks of this batch
  {
    float* fl = &flags[(b << 8) + t];
    while (__float_as_uint(atomicAdd(fl, 0.0f)) != MAGICU)
      __builtin_amdgcn_s_sleep(2);
  }
  __syncthreads();

  // ========== Stage B: redundant conv+BN+ReLU+dots+sigmoids (per block)
  // thread: position p = t&127 (seg=p>>6, pos=p&63), o-half oh = t>>7.
  {
    int p = t & 127;
    int oh = __builtin_amdgcn_readfirstlane(t >> 7);   // wave-uniform
    int seg = p >> 6, pos = p & 63;
    const float* yrow = xhT + (((b * 2 + seg) * 64 + pos) << 8);
    const float* wb = w1 + oh * 8 * C_;                // uniform -> s_loads
    float r8[8] = {0, 0, 0, 0, 0, 0, 0, 0};
    #pragma unroll 4
    for (int c4 = 0; c4 < 64; ++c4) {
      float4 y4 = *(const float4*)&yrow[c4 * 4];
      const float ye[4] = {y4.x, y4.y, y4.z, y4.w};
      #pragma unroll
      for (int e = 0; e < 4; ++e) {
        int cc = c4 * 4 + e;
        #pragma unroll
        for (int oo = 0; oo < 8; ++oo)
          r8[oo] = fmaf(wb[oo * C_ + cc], ye[e], r8[oo]);
      }
    }
    float dH = 0, dW = 0, dD1 = 0, dD2 = 0;
    #pragma unroll
    for (int oo = 0; oo < 8; ++oo) {
      int o = oh * 8 + oo;
      float sc = gam[o] * rsqrtf(var[o] + 1e-5f);
      float y = r8[oo] + b1[o] - mea[o];
      float rr = fmaxf(fmaf(y, sc, bet[o]), 0.0f);
      dH = fmaf(wh[o], rr, dH);
      dW = fmaf(ww[o], rr, dW);
      dD1 = fmaf(wd1[o], rr, dD1);
      dD2 = fmaf(wd2[o], rr, dD2);
    }
    dpart[oh][p][0] = dH; dpart[oh][p][1] = dW;
    dpart[oh][p][2] = dD1; dpart[oh][p][3] = dD2;
  }
  __syncthreads();
  if (t < 128) {
    int seg = t >> 6, pos = t & 63;
    float aH = bh[0] + dpart[0][t][0] + dpart[1][t][0];
    float aW = bw[0] + dpart[0][t][1] + dpart[1][t][1];
    float aD1 = bd1[0] + dpart[0][t][2] + dpart[1][t][2];
    float aD2 = bd2[0] + dpart[0][t][3] + dpart[1][t][3];
    if (seg == 0) {
      ahs[pos] = sigm(aH);
      sds[pos] = sigm(aD1) * sigm(aD2);
    } else {
      sws[pos] = sigm(aW);
    }
  }
  __syncthreads();
  if (t < 64) sps[t] = sws[t] * sds[t];
  __syncthreads();

  // ========== Stage C: selection + moments + output (k_fin body)
  float4 sp4 = *(const float4*)&sps[(t * 4) & 63];
  const float spe[4] = {sp4.x, sp4.y, sp4.z, sp4.w};
  float ahv[4];
  #pragma unroll
  for (int it = 0; it < 4; ++it) ahv[it] = ahs[it * 16 + (t >> 4)];

  float v[16];
  #pragma unroll
  for (int it = 0; it < 4; ++it)
    #pragma unroll
    for (int e = 0; e < 4; ++e) v[it * 4 + e] = ahv[it] * spe[e];

  float mn = v[0], mx = v[0];
  #pragma unroll
  for (int k = 1; k < 16; ++k) { mn = fminf(mn, v[k]); mx = fmaxf(mx, v[k]); }
  #pragma unroll
  for (int o = 32; o; o >>= 1) {
    mn = fminf(mn, __shfl_xor(mn, o, 64));
    mx = fmaxf(mx, __shfl_xor(mx, o, 64));
  }
  if ((t & 63) == 0) { fmn[t >> 6] = mn; fmx[t >> 6] = mx; }
  __syncthreads();
  mn = fminf(fminf(fmn[0], fmn[1]), fminf(fmn[2], fmn[3]));
  mx = fmaxf(fmaxf(fmx[0], fmx[1]), fmaxf(fmx[2], fmx[3]));

  unsigned lo = __float_as_uint(mn);        // cnt_ge(lo) = 4096 >= K
  unsigned hi = __float_as_uint(mx) + 1u;   // cnt_ge(hi) = 0 < K
  while (hi - lo > 8192u) {
    unsigned mid = lo + ((hi - lo) >> 1);
    float midf = __uint_as_float(mid);
    int cnt = 0;
    #pragma unroll
    for (int k = 0; k < 16; ++k) cnt += (v[k] >= midf) ? 1 : 0;
    #pragma unroll
    for (int o = 32; o; o >>= 1) cnt += __shfl_xor(cnt, o, 64);
    if ((t & 63) == 0) icomb[t >> 6] = cnt;
    __syncthreads();
    int total = icomb[0] + icomb[1] + icomb[2] + icomb[3];
    __syncthreads();
    if (total >= K_SEL) lo = mid; else hi = mid;
  }
  float thr = __uint_as_float(lo);
  float gm = sigm(msk[0]);

  // acc[0..6] = q1..q7, acc[7] = T, acc[8..14] = P1..P7
  float acc[15];
  #pragma unroll
  for (int m = 0; m < 15; ++m) acc[m] = 0.0f;
  #pragma unroll
  for (int it = 0; it < 4; ++it) {
    const float xe[4] = {xv[it].x, xv[it].y, xv[it].z, xv[it].w};
    #pragma unroll
    for (int e = 0; e < 4; ++e) {
      float vv = v[it * 4 + e];
      float xx = xe[e];
      acc[7] += xx;
      if (vv >= thr) {
        float p = vv;
        acc[0] += p;
        acc[8] = fmaf(p, xx, acc[8]); p *= vv;
        acc[1] += p;
        acc[9] = fmaf(p, xx, acc[9]); p *= vv;
        acc[2] += p;
        acc[10] = fmaf(p, xx, acc[10]); p *= vv;
        acc[3] += p;
        acc[11] = fmaf(p, xx, acc[11]); p *= vv;
        acc[4] += p;
        acc[12] = fmaf(p, xx, acc[12]); p *= vv;
        acc[5] += p;
        acc[13] = fmaf(p, xx, acc[13]); p *= vv;
        acc[6] += p;
        acc[14] = fmaf(p, xx, acc[14]);
      }
    }
  }
  #pragma unroll
  for (int m = 0; m < 15; ++m) {
    float s = acc[m];
    #pragma unroll
    for (int o = 32; o; o >>= 1) s += __shfl_xor(s, o, 64);
    if ((t & 63) == 0) red[m][t >> 6] = s;
  }
  __syncthreads();
  if (t < 15) {
    const float invf[15] = {1.0f, 0.5f, 1.0f / 6.0f, 1.0f / 24.0f,
                            1.0f / 120.0f, 1.0f / 720.0f, 1.0f / 5040.0f,
                            1.0f,
                            1.0f, 0.5f, 1.0f / 6.0f, 1.0f / 24.0f,
                            1.0f / 120.0f, 1.0f / 720.0f, 1.0f / 5040.0f};
    ps[t] = (red[t][0] + red[t][1] + red[t][2] + red[t][3]) * invf[t];
  }
  __syncthreads();
  float q1 = ps[0], q2 = ps[1], q3 = ps[2], q4 = ps[3];
  float q5 = ps[4], q6 = ps[5], q7 = ps[6];
  float T = ps[7];
  float p1 = ps[8], p2 = ps[9], p3 = ps[10], p4 = ps[11];
  float p5 = ps[12], p6 = ps[13], p7 = ps[14];

  float* ob = out + (size_t)bc * N_;
  #pragma unroll
  for (int it = 0; it < 4; ++it) {
    float o4[4];
    #pragma unroll
    for (int e = 0; e < 4; ++e) {
      float alpha = gm * v[it * 4 + e];
      float hn = p7;
      hn = fmaf(alpha, hn, p6);
      hn = fmaf(alpha, hn, p5);
      hn = fmaf(alpha, hn, p4);
      hn = fmaf(alpha, hn, p3);
      hn = fmaf(alpha, hn, p2);
      hn = fmaf(alpha, hn, p1);
      float numer = fmaf(alpha, hn, T);
      float hd = q7;
      hd = fmaf(alpha, hd, q6);
      hd = fmaf(alpha, hd, q5);
      hd = fmaf(alpha, hd, q4);
      hd = fmaf(alpha, hd, q3);
      hd = fmaf(alpha, hd, q2);
      hd = fmaf(alpha, hd, q1);
      float denom = fmaf(alpha, hd, (float)N_);
      o4[e] = numer / denom;
    }
    *(float4*)&ob[it * 1024 + t * 4] = make_float4(o4[0], o4[1], o4[2], o4[3]);
  }
}

extern "C" void kernel_launch(void* const* d_in, const int* in_sizes, int n_in,
                              void* d_out, int out_size, void* d_ws, size_t ws_size,
                              hipStream_t stream) {
  (void)in_sizes; (void)n_in; (void)out_size; (void)ws_size;
  const float* x   = (const float*)d_in[0];
  const float* w1  = (const float*)d_in[1];
  const float* b1  = (const float*)d_in[2];
  const float* gam = (const float*)d_in[3];
  const float* bet = (const float*)d_in[4];
  const float* mea = (const float*)d_in[5];
  const float* var = (const float*)d_in[6];
  const float* wh  = (const float*)d_in[7];
  const float* bh  = (const float*)d_in[8];
  const float* ww  = (const float*)d_in[9];
  const float* bw  = (const float*)d_in[10];
  const float* wd1 = (const float*)d_in[11];
  const float* bd1 = (const float*)d_in[12];
  const float* wd2 = (const float*)d_in[13];
  const float* bd2 = (const float*)d_in[14];
  const float* msk = (const float*)d_in[15];
  float* out = (float*)d_out;

  float* ws    = (float*)d_ws;
  float* xhT   = ws;                 // 65536 floats
  float* flags = ws + 65536;         // 512

  hipLaunchKernelGGL(k_all, dim3(B_ * C_), dim3(256), 0, stream,
                     x, w1, b1, gam, bet, mea, var,
                     wh, bh, ww, bw, wd1, bd1, wd2, bd2, msk,
                     xhT, flags, out);
}